// Round 1
// 260.238 us; speedup vs baseline: 1.0141x; 1.0141x over previous
//
#include <hip/hip_runtime.h>
#include <stdint.h>

#define NDIM 512
#define HEADS 8
#define DHEAD 64
#define NSEQ 4096
#define BATCH 8
#define ROWS (BATCH * NSEQ)   // 32768
#define QKVN (3 * NDIM)       // 1536

typedef unsigned short ushort_t;
typedef __bf16 bf16x8 __attribute__((ext_vector_type(8)));
typedef float f32x4 __attribute__((ext_vector_type(4)));
typedef unsigned short u16x8 __attribute__((ext_vector_type(8)));
typedef unsigned short u16x4 __attribute__((ext_vector_type(4)));

__device__ __forceinline__ ushort_t f2bf(float f) {
  union { float f; uint32_t u; } v; v.f = f;
  uint32_t r = (v.u + 0x7FFFu + ((v.u >> 16) & 1u)) >> 16;
  return (ushort_t)r;
}
__device__ __forceinline__ float bf2f(ushort_t h) {
  union { uint32_t u; float f; } v; v.u = ((uint32_t)h) << 16;
  return v.f;
}

__device__ __forceinline__ void gload_lds16(const void* g, void* l) {
  __builtin_amdgcn_global_load_lds(
      (__attribute__((address_space(1))) void*)(g),
      (__attribute__((address_space(3))) void*)(l), 16, 0, 0);
}

// ---------- prep: coalesced LDS-tile transpose+cast of weights ----------
__global__ __launch_bounds__(256) void prep_k(const float* __restrict__ w_qkv,
                                              const float* __restrict__ w_out,
                                              ushort_t* __restrict__ wqkvT,
                                              ushort_t* __restrict__ woutT) {
  __shared__ float tile[32][33];
  int id = blockIdx.x;
  const float* src;
  ushort_t* dst;
  int srcStride, ni, ki;
  if (id < 768) {               // 48 n-tiles x 16 k-tiles
    ni = id % 48; ki = id / 48; src = w_qkv; dst = wqkvT; srcStride = QKVN;
  } else {
    id -= 768;                  // 16 x 16
    ni = id % 16; ki = id / 16; src = w_out; dst = woutT; srcStride = NDIM;
  }
  int tr = threadIdx.x >> 3;          // 0..31
  int tc = (threadIdx.x & 7) * 4;     // 0..28
  float4 v = *(const float4*)(src + (size_t)(ki * 32 + tr) * srcStride + ni * 32 + tc);
  tile[tr][tc] = v.x; tile[tr][tc + 1] = v.y; tile[tr][tc + 2] = v.z; tile[tr][tc + 3] = v.w;
  __syncthreads();
  u16x4 o;
  o[0] = f2bf(tile[tc + 0][tr]);
  o[1] = f2bf(tile[tc + 1][tr]);
  o[2] = f2bf(tile[tc + 2][tr]);
  o[3] = f2bf(tile[tc + 3][tr]);
  *(u16x4*)(dst + (size_t)(ni * 32 + tr) * NDIM + ki * 32 + tc) = o;
}

// ---------- rmsnorm ----------
__global__ __launch_bounds__(256) void rmsnorm_k(const float* __restrict__ x,
                                                 const float* __restrict__ gamma,
                                                 ushort_t* __restrict__ xn) {
  int wave = threadIdx.x >> 6, lane = threadIdx.x & 63;
  size_t row = (size_t)blockIdx.x * 4 + wave;
  const float4* xr = (const float4*)(x + row * NDIM);
  float4 v0 = xr[lane * 2], v1 = xr[lane * 2 + 1];
  float s = v0.x*v0.x + v0.y*v0.y + v0.z*v0.z + v0.w*v0.w
          + v1.x*v1.x + v1.y*v1.y + v1.z*v1.z + v1.w*v1.w;
#pragma unroll
  for (int off = 32; off; off >>= 1) s += __shfl_xor(s, off, 64);
  float scale = 22.627416997969522f / fmaxf(sqrtf(s), 1e-12f);
  const float4* gr = (const float4*)gamma;
  float4 g0 = gr[lane * 2], g1 = gr[lane * 2 + 1];
  u16x8 o;
  o[0] = f2bf(v0.x * scale * g0.x);
  o[1] = f2bf(v0.y * scale * g0.y);
  o[2] = f2bf(v0.z * scale * g0.z);
  o[3] = f2bf(v0.w * scale * g0.w);
  o[4] = f2bf(v1.x * scale * g1.x);
  o[5] = f2bf(v1.y * scale * g1.y);
  o[6] = f2bf(v1.z * scale * g1.z);
  o[7] = f2bf(v1.w * scale * g1.w);
  *(u16x8*)(xn + row * NDIM + lane * 8) = o;
}

// ---------------------------------------------------------------------------
// 256x128 counted-vmcnt GEMM core (T3+T4+T2+T5).
// 512 threads = 8 waves (4M x 2N), wave tile 64x64, BK=64, K=512 (8 K-tiles).
// LDS ring of 3 K-tile buffers: A 3x32KB + B 3x16KB = 144KB.
// Staging for tile t+2 issued during tile t (6 gload_lds/thread/tile, uniform
// order) -> steady-state wait is vmcnt(6) once per K-tile; drains to 0 only at
// t==6. Raw s_barrier (no implicit vmcnt drain). XOR-8 pre-swizzled staging,
// conflict-free (2-way) ds_read_b128 frag reads. setprio(1) around MFMA.
// ---------------------------------------------------------------------------
template <bool OUT_BF16>
__device__ __forceinline__ void gemm256x128_core(
    const ushort_t* __restrict__ A, size_t strideA, size_t m0,
    const ushort_t* __restrict__ B,   // 128 rows of length 512 (row = n)
    void* __restrict__ C, size_t strideC, size_t n0,
    ushort_t* sm) {
  const int tid  = threadIdx.x;
  const int lane = tid & 63;
  const int wave = tid >> 6;
  const int srow = lane >> 3;                 // 0..7
  const int scol = ((lane & 7) ^ srow) * 16;  // pre-swizzled source byte col
  const int r = lane & 15, q = lane >> 4;
  const int wm = (wave >> 1) * 64;            // 0,64,128,192
  const int wn = (wave & 1) * 64;             // 0,64

  ushort_t* As = sm;              // 3 * 16384 ushorts (3 x 32KB)
  ushort_t* Bs = sm + 49152;      // 3 * 8192 ushorts  (3 x 16KB)

  auto stageA = [&](int t2, int g) {          // g in [0,32): 8-row group
    gload_lds16((const char*)(A + (m0 + (size_t)(g * 8 + srow)) * strideA + t2 * 64) + scol,
                (char*)(As + (t2 % 3) * 16384 + g * 512));
  };
  auto stageB = [&](int t2, int g) {          // g in [0,16)
    gload_lds16((const char*)(B + (size_t)(g * 8 + srow) * NDIM + t2 * 64) + scol,
                (char*)(Bs + (t2 % 3) * 8192 + g * 512));
  };

  // prologue: stage K-tiles 0 and 1 (12 loads/thread), wait first 6 (tile 0)
#pragma unroll
  for (int t2 = 0; t2 < 2; ++t2) {
#pragma unroll
    for (int a = 0; a < 4; ++a) stageA(t2, wave * 4 + a);
#pragma unroll
    for (int bb = 0; bb < 2; ++bb) stageB(t2, wave * 2 + bb);
  }
  asm volatile("s_waitcnt vmcnt(6)" ::: "memory");
  __builtin_amdgcn_s_barrier();

  f32x4 acc[4][4] = {};

#pragma unroll
  for (int t = 0; t < 8; ++t) {
    const ushort_t* Ab = As + (t % 3) * 16384;
    const ushort_t* Bb = Bs + (t % 3) * 8192;
#pragma unroll
    for (int ph = 0; ph < 2; ++ph) {
      const int kb = ph * 4 + q;
      bf16x8 af[4], bfr[4];
#pragma unroll
      for (int i = 0; i < 4; ++i) {
        int row = wm + i * 16 + r;
        af[i] = *(const bf16x8*)(const void*)(Ab + row * 64 + ((kb ^ (row & 7)) << 3));
      }
#pragma unroll
      for (int j = 0; j < 4; ++j) {
        int row = wn + j * 16 + r;
        bfr[j] = *(const bf16x8*)(const void*)(Bb + row * 64 + ((kb ^ (row & 7)) << 3));
      }
      if (t < 6) {                 // stage tile t+2 (3 loads this phase)
        int t2 = t + 2;
        if (ph == 0) { stageA(t2, wave * 4 + 0); stageA(t2, wave * 4 + 1); stageB(t2, wave * 2 + 0); }
        else         { stageA(t2, wave * 4 + 2); stageA(t2, wave * 4 + 3); stageB(t2, wave * 2 + 1); }
      }
      __builtin_amdgcn_s_barrier();
      asm volatile("s_waitcnt lgkmcnt(0)" ::: "memory");
      __builtin_amdgcn_s_setprio(1);
#pragma unroll
      for (int i = 0; i < 4; ++i)
#pragma unroll
        for (int j = 0; j < 4; ++j)
          acc[i][j] = __builtin_amdgcn_mfma_f32_16x16x32_bf16(af[i], bfr[j], acc[i][j], 0, 0, 0);
      __builtin_amdgcn_s_setprio(0);
      if (ph == 1) {
        if (t < 6)       { asm volatile("s_waitcnt vmcnt(6)" ::: "memory"); }
        else if (t == 6) { asm volatile("s_waitcnt vmcnt(0)" ::: "memory"); }
      }
      __builtin_amdgcn_s_barrier();
    }
  }

  // epilogue (LDS bounce, full drain is fine once per block)
  __syncthreads();
  if constexpr (OUT_BF16) {
    ushort_t* Cb = sm;                      // [256][136] bf16 = 69632 B
    ushort_t* Cc = (ushort_t*)C;
#pragma unroll
    for (int i = 0; i < 4; ++i)
#pragma unroll
      for (int j = 0; j < 4; ++j)
#pragma unroll
        for (int v = 0; v < 4; ++v)
          Cb[(wm + i * 16 + q * 4 + v) * 136 + wn + j * 16 + r] = f2bf(acc[i][j][v]);
    __syncthreads();
#pragma unroll
    for (int it = 0; it < 8; ++it) {
      int row = (tid >> 4) + it * 32;
      int col = (tid & 15) * 8;
      u16x8 val = *(const u16x8*)(Cb + row * 136 + col);
      *(u16x8*)(Cc + (m0 + row) * strideC + n0 + col) = val;
    }
  } else {
    float* Cf = (float*)sm;                 // [128][132] f32 = 67584 B
    float* Co = (float*)C;
#pragma unroll
    for (int p = 0; p < 2; ++p) {
      __syncthreads();
      if (((wave >> 2) & 1) == p) {
#pragma unroll
        for (int i = 0; i < 4; ++i)
#pragma unroll
          for (int j = 0; j < 4; ++j)
#pragma unroll
            for (int v = 0; v < 4; ++v)
              Cf[((wm & 127) + i * 16 + q * 4 + v) * 132 + wn + j * 16 + r] = acc[i][j][v];
      }
      __syncthreads();
      int row = tid >> 2;
      int c0 = (tid & 3) * 4;
#pragma unroll
      for (int it = 0; it < 8; ++it) {
        int col = c0 + it * 16;
        f32x4 val = *(const f32x4*)(Cf + row * 132 + col);
        *(f32x4*)(Co + (m0 + p * 128 + row) * strideC + n0 + col) = val;
      }
    }
  }
}

// ---------- QKV GEMM: qkv = xn[32768,512] @ wqkvT[1536,512]^T, bf16 out ----------
__global__ __launch_bounds__(512, 2) void gemm_qkv(const ushort_t* __restrict__ A,
                                                   const ushort_t* __restrict__ BT,
                                                   ushort_t* __restrict__ C) {
  __shared__ __align__(16) ushort_t sm[73728];   // 144 KB
  const int flat = blockIdx.x;           // 1536 blocks
  const int xcd = flat & 7;
  const int idx = flat >> 3;             // 0..191
  const int local_m = idx / 12;          // 0..15
  const int n_t = idx - local_m * 12;    // 0..11
  const size_t m0 = (size_t)(xcd * 16 + local_m) * 256;
  const size_t n0 = (size_t)n_t * 128;
  gemm256x128_core<true>(A, NDIM, m0, BT + n0 * NDIM, C, QKVN, n0, sm);
}

// ---------- gram partial: G[d,e] += sum_n Q[n,d]K[n,e], + col sumsq ----------
__global__ __launch_bounds__(256) void gram_k(const ushort_t* __restrict__ qkv,
                                              float* __restrict__ pG,
                                              float* __restrict__ pSq) {
  int chunk = blockIdx.x;  // 0..7
  int bh = blockIdx.y;     // 0..63
  int b = bh >> 3, h = bh & 7;
  __shared__ ushort_t Qt[64 * 72];
  __shared__ ushort_t Kt[64 * 72];
  __shared__ float sq[128];
  int tid = threadIdx.x, lane = tid & 63, wave = tid >> 6;
  int nl = tid >> 2;
  int dp = (tid & 3) * 16;
  int r = lane & 15, q = lane >> 4;
  float aq[16] = {}, ak[16] = {};
  f32x4 acc[4] = {};
  size_t base_row = ((size_t)b * NSEQ + (size_t)chunk * 512) * QKVN + (size_t)h * DHEAD;
  int swz_n = ((nl >> 3) & 7);
  int c_lo = (nl & 7) | (((swz_n ^ (dp >> 3)) & 7) << 3);
  int c_hi = (nl & 7) | (((swz_n ^ ((dp >> 3) + 1)) & 7) << 3);
  ushort_t* qlo = Qt + dp * 72 + c_lo;
  ushort_t* qhi = Qt + (dp + 8) * 72 + c_hi;
  ushort_t* klo = Kt + dp * 72 + c_lo;
  ushort_t* khi = Kt + (dp + 8) * 72 + c_hi;

  for (int sc = 0; sc < 8; ++sc) {
    __syncthreads();
    size_t g = base_row + (size_t)(sc * 64 + nl) * QKVN;
    u16x8 qv0 = *(const u16x8*)(qkv + g + dp);
    u16x8 qv1 = *(const u16x8*)(qkv + g + dp + 8);
    u16x8 kv0 = *(const u16x8*)(qkv + g + NDIM + dp);
    u16x8 kv1 = *(const u16x8*)(qkv + g + NDIM + dp + 8);
#pragma unroll
    for (int i = 0; i < 8; ++i) {
      float fq = bf2f(qv0[i]); aq[i] += fq * fq;       qlo[i * 72] = qv0[i];
      float fq2 = bf2f(qv1[i]); aq[8 + i] += fq2 * fq2; qhi[i * 72] = qv1[i];
      float fk = bf2f(kv0[i]); ak[i] += fk * fk;       klo[i * 72] = kv0[i];
      float fk2 = bf2f(kv1[i]); ak[8 + i] += fk2 * fk2; khi[i * 72] = kv1[i];
    }
    __syncthreads();
#pragma unroll
    for (int ks = 0; ks < 64; ks += 32) {
      int kb = (ks >> 3) + q;
      int m = wave * 16 + r;
      bf16x8 a = *(const bf16x8*)(const void*)(Qt + m * 72 + (((kb ^ (m >> 3)) & 7) << 3));
#pragma unroll
      for (int j = 0; j < 4; ++j) {
        int e = j * 16 + r;
        bf16x8 bb = *(const bf16x8*)(const void*)(Kt + e * 72 + (((kb ^ (e >> 3)) & 7) << 3));
        acc[j] = __builtin_amdgcn_mfma_f32_16x16x32_bf16(a, bb, acc[j], 0, 0, 0);
      }
    }
  }
  size_t gbase = ((size_t)bh * 8 + chunk) * 4096;
#pragma unroll
  for (int j = 0; j < 4; ++j)
#pragma unroll
    for (int v = 0; v < 4; ++v)
      pG[gbase + (size_t)(wave * 16 + q * 4 + v) * 64 + j * 16 + r] = acc[j][v];
  if (tid < 128) sq[tid] = 0.f;
  __syncthreads();
#pragma unroll
  for (int i = 0; i < 16; ++i) {
    atomicAdd(&sq[dp + i], aq[i]);
    atomicAdd(&sq[64 + dp + i], ak[i]);
  }
  __syncthreads();
  if (tid < 128) pSq[((size_t)bh * 8 + chunk) * 128 + tid] = sq[tid];
}

// ---------- softmax -> attnT bf16 [bh][e][d] (transposed for w2t) ----------
__global__ __launch_bounds__(256) void softmax_k(const float* __restrict__ pG,
                                                 const float* __restrict__ pSq,
                                                 const float* __restrict__ temp,
                                                 ushort_t* __restrict__ attnT) {
  int bh = blockIdx.x;
  int h = bh & 7;
  int t = threadIdx.x;
  int d = t >> 2;
  int eg = (t & 3) * 16;
  __shared__ float kn[64];
  if (t < 64) {
    float sk = 0.f;
    for (int c = 0; c < 8; ++c) sk += pSq[((size_t)bh * 8 + c) * 128 + 64 + t];
    kn[t] = fmaxf(sqrtf(sk), 1e-12f);
  }
  float sq = 0.f;
  for (int c = 0; c < 8; ++c) sq += pSq[((size_t)bh * 8 + c) * 128 + d];
  float qn = fmaxf(sqrtf(sq), 1e-12f);
  __syncthreads();
  float scale = 8.0f * expf(temp[h]) / qn;
  float row[16];
#pragma unroll
  for (int k = 0; k < 16; ++k) row[k] = 0.f;
  for (int c = 0; c < 8; ++c) {
    const float4* src = (const float4*)(pG + ((size_t)bh * 8 + c) * 4096 + d * 64 + eg);
#pragma unroll
    for (int k4 = 0; k4 < 4; ++k4) {
      float4 v = src[k4];
      row[k4 * 4 + 0] += v.x; row[k4 * 4 + 1] += v.y;
      row[k4 * 4 + 2] += v.z; row[k4 * 4 + 3] += v.w;
    }
  }
#pragma unroll
  for (int k = 0; k < 16; ++k) row[k] = row[k] * scale / kn[eg + k];
  float mx = -1e30f;
#pragma unroll
  for (int k = 0; k < 16; ++k) mx = fmaxf(mx, row[k]);
  mx = fmaxf(mx, __shfl_xor(mx, 1, 64));
  mx = fmaxf(mx, __shfl_xor(mx, 2, 64));
  float s = 0.f;
#pragma unroll
  for (int k = 0; k < 16; ++k) { row[k] = expf(row[k] - mx); s += row[k]; }
  s += __shfl_xor(s, 1, 64);
  s += __shfl_xor(s, 2, 64);
  float inv = 1.0f / s;
#pragma unroll
  for (int k = 0; k < 16; ++k)
    attnT[(size_t)bh * 4096 + (eg + k) * 64 + d] = f2bf(row[k] * inv);
}

// ---------- W2T[b][c][h*64+e] = sum_d woutT[c][h*64+d] * attnT[bh][e][d] ----------
__global__ __launch_bounds__(256) void w2t_k(const ushort_t* __restrict__ woutT,
                                             const ushort_t* __restrict__ attnT,
                                             ushort_t* __restrict__ W2T) {
  int mq = blockIdx.x;      // 0..3 (128 rows of c each)
  int bh = blockIdx.y;
  int b = bh >> 3, h = bh & 7;
  int tid = threadIdx.x, lane = tid & 63, wave = tid >> 6;
  int r = lane & 15, q = lane >> 4;
  int mbase = mq * 128 + wave * 32;
  const ushort_t* At = attnT + (size_t)bh * 4096;
  f32x4 acc[2][4] = {};
#pragma unroll
  for (int kk = 0; kk < 64; kk += 32) {
    bf16x8 a[2], bb[4];
#pragma unroll
    for (int mf = 0; mf < 2; ++mf)
      a[mf] = *(const bf16x8*)(woutT + (size_t)(mbase + mf * 16 + r) * NDIM + h * 64 + kk + q * 8);
#pragma unroll
    for (int nf = 0; nf < 4; ++nf)
      bb[nf] = *(const bf16x8*)(At + (nf * 16 + r) * 64 + kk + q * 8);
#pragma unroll
    for (int mf = 0; mf < 2; ++mf)
#pragma unroll
      for (int nf = 0; nf < 4; ++nf)
        acc[mf][nf] = __builtin_amdgcn_mfma_f32_16x16x32_bf16(a[mf], bb[nf], acc[mf][nf], 0, 0, 0);
  }
#pragma unroll
  for (int mf = 0; mf < 2; ++mf)
#pragma unroll
    for (int nf = 0; nf < 4; ++nf)
#pragma unroll
      for (int v = 0; v < 4; ++v)
        W2T[(size_t)b * 262144 + (size_t)(mbase + mf * 16 + q * 4 + v) * NDIM +
            h * 64 + nf * 16 + r] = f2bf(acc[mf][nf][v]);
}

// ---------- final: out[b] = V[b] @ W2T[b]^T  (V read from qkv, f32 out) ----------
__global__ __launch_bounds__(512, 2) void gemm_v(const ushort_t* __restrict__ qkv,
                                                 const ushort_t* __restrict__ W2T,
                                                 float* __restrict__ out) {
  __shared__ __align__(16) ushort_t sm[73728];   // 144 KB
  const int flat = blockIdx.x;           // 512 blocks: xcd = b
  const int b = flat & 7;
  const int local = flat >> 3;           // 0..63
  const int mt = local >> 2, nt = local & 3;
  const size_t m0 = (size_t)b * NSEQ + (size_t)mt * 256;
  const size_t n0 = (size_t)nt * 128;
  gemm256x128_core<false>(qkv + 1024, QKVN, m0,
                          W2T + (size_t)b * 262144 + n0 * NDIM,
                          out, NDIM, n0, sm);
}

extern "C" void kernel_launch(void* const* d_in, const int* in_sizes, int n_in,
                              void* d_out, int out_size, void* d_ws, size_t ws_size,
                              hipStream_t stream) {
  (void)in_sizes; (void)n_in; (void)out_size; (void)ws_size;
  const float* x     = (const float*)d_in[0];
  const float* gamma = (const float*)d_in[1];
  const float* w_qkv = (const float*)d_in[2];
  const float* temp  = (const float*)d_in[3];
  const float* w_out = (const float*)d_in[4];
  float* out = (float*)d_out;
  char* ws = (char*)d_ws;

  // workspace layout (~136.8 MB peak, unchanged):
  // [0, 96MB)        qkv bf16 [32768][1536]
  // [96MB, 128MB)    xn bf16; after gemm1: pG (8MB) + pSq (0.25MB) + W2T (4MB @ +12MB)
  // [128MB, ...)     wqkvT (1.5MB), woutT (0.5MB), attnT (0.5MB)
  ushort_t* qkv   = (ushort_t*)ws;
  ushort_t* xn    = (ushort_t*)(ws + (size_t)100663296);
  float*    pG    = (float*)(ws + (size_t)100663296);
  float*    pSq   = (float*)(ws + (size_t)100663296 + 8388608);
  ushort_t* W2T   = (ushort_t*)(ws + (size_t)100663296 + 12582912);
  ushort_t* wqkvT = (ushort_t*)(ws + (size_t)134217728);
  ushort_t* woutT = (ushort_t*)(ws + (size_t)134217728 + 1572864);
  ushort_t* attnT = (ushort_t*)(ws + (size_t)134217728 + 2097152);

  prep_k<<<1024, 256, 0, stream>>>(w_qkv, w_out, wqkvT, woutT);
  rmsnorm_k<<<ROWS / 4, 256, 0, stream>>>(x, gamma, xn);
  gemm_qkv<<<(QKVN / 128) * (ROWS / 256), 512, 0, stream>>>(xn, wqkvT, qkv);
  gram_k<<<dim3(8, 64), 256, 0, stream>>>(qkv, pG, pSq);
  softmax_k<<<64, 256, 0, stream>>>(pG, pSq, temp, attnT);
  w2t_k<<<dim3(4, 64), 256, 0, stream>>>(woutT, attnT, W2T);
  gemm_v<<<(NDIM / 128) * (ROWS / 256), 512, 0, stream>>>(qkv, W2T, out);
}